// Round 3
// baseline (899.380 us; speedup 1.0000x reference)
//
#include <hip/hip_runtime.h>
#include <math.h>

// Problem constants
#define NB  262144   // batch
#define SD  128      // STATE_DIM
#define HID 256      // HIDDEN
#define AD  8        // ACTION_DIM

typedef float v2f __attribute__((ext_vector_type(2)));

// d_ws layout (floats)
#define W1T_OFF 0                       // [SD][HID]   W1T[k*HID+j] = W1[j*SD+k]
#define W2T_OFF (SD*HID)                // [HID][HID]  32768
#define W3P_OFF (W2T_OFF + HID*HID)     // [HID][AD] float2 pairs (u,s): 98304, 4096 floats
#define B1_OFF  (W3P_OFF + HID*2*AD)    // 102400
#define B2_OFF  (B1_OFF + HID)          // 102656
#define B3P_OFF (B2_OFF + HID)          // 102912, [AD] float2 pairs
#define WS_FLOATS (B3P_OFF + 2*AD)      // 102928 floats = 411,712 bytes

__global__ __launch_bounds__(256) void prep_weights(
    const float* __restrict__ W1, const float* __restrict__ b1,
    const float* __restrict__ W2, const float* __restrict__ b2,
    const float* __restrict__ W3, const float* __restrict__ b3,
    float* __restrict__ ws) {
  int stride = gridDim.x * blockDim.x;
  for (int i = blockIdx.x * blockDim.x + threadIdx.x; i < WS_FLOATS; i += stride) {
    float v;
    if (i < W2T_OFF) {                       // W1T
      int k = i >> 8, j = i & 255;
      v = W1[j * SD + k];
    } else if (i < W3P_OFF) {                // W2T
      int t = i - W2T_OFF;
      int k = t >> 8, j = t & 255;
      v = W2[j * HID + k];
    } else if (i < B1_OFF) {                 // W3P[k][a] = (W3[a][k], W3[a+8][k])
      int t = i - W3P_OFF;
      int k = t >> 4, a = (t >> 1) & 7, h = t & 1;
      v = W3[(a + 8 * h) * HID + k];
    } else if (i < B2_OFF) {
      v = b1[i - B1_OFF];
    } else if (i < B3P_OFF) {
      v = b2[i - B2_OFF];
    } else {                                 // B3P[a] = (b3[a], b3[a+8])
      int t = i - B3P_OFF;
      v = b3[(t >> 1) + 8 * (t & 1)];
    }
    ws[i] = v;
  }
}

// R7 post-mortem of R6: (a) v_pk_fma_f32 is VALU-port-time NEUTRAL on CDNA4
// (instr count halved, VALUBusy*dur unchanged; fp32 peak 157.3 TF is the
// unpacked rate) -> reverted to the proven fmaf codegen. (b) The (256,5)
// bound + v2f asm operands spilled: VGPR 52->48 with ~90 live values, and
// WRITE_SIZE showed +40 MB of scratch evictions. (c) Occupancy never moved.
//
// R7 lever: TLP via finer workgroup granularity. 128-thread blocks (2 waves),
// 8 rows/wave, 16 rows/block -> LDS [16][256] = 16 KiB/block -> up to 10
// blocks/CU = 20 waves/CU (62.5% vs 50% cap before). Per-WAVE weight traffic
// unchanged (8 rows/wave), so L2 weight load stays ~12.6 GB. XOR float4-group
// layout (g ^ r, r = wave-local row 0..7) replaces the +8 pad: layer-2 reads
// stay wave-uniform broadcasts, layer-3's 8 row-slices land on 8 banks.
// Wave-private rows -> NO barriers anywhere.
__global__ __launch_bounds__(128, 5) void actor_fused(
    const float* __restrict__ state, const float* __restrict__ eps,
    const float* __restrict__ ws, int* __restrict__ out) {
  __shared__ float s_h[16][256];   // 16,384 B

  const int tid  = threadIdx.x;
  const int lane = tid & 63;
  const int wvu  = __builtin_amdgcn_readfirstlane(tid >> 6);  // 0..1, uniform
  const long wrow = (long)blockIdx.x * 16 + wvu * 8;          // wave's first row

  const float4* __restrict__ W1T4 = (const float4*)(ws + W1T_OFF);  // [SD][64]
  const float4* __restrict__ W2T4 = (const float4*)(ws + W2T_OFF);  // [HID][64]
  const v2f*    __restrict__ W3P  = (const v2f*)(ws + W3P_OFF);     // [HID][8]

  const float* __restrict__ xbase = state + wrow * SD;   // uniform pointer

  // ---- layer 1: h1 = relu(x @ W1^T + b1), K = 128
  float acc[8][4];
  #pragma unroll
  for (int r = 0; r < 8; ++r)
    #pragma unroll
    for (int c = 0; c < 4; ++c) acc[r][c] = 0.0f;

  #pragma unroll 2
  for (int k0 = 0; k0 < SD; k0 += 4) {
    float4 w[4];
    #pragma unroll
    for (int j = 0; j < 4; ++j) w[j] = W1T4[(k0 + j) * 64 + lane];
    float4 xv[8];
    #pragma unroll
    for (int r = 0; r < 8; ++r)                       // uniform address: one line
      xv[r] = *(const float4*)(xbase + r * SD + k0);  // serves the whole wave
    #pragma unroll
    for (int j = 0; j < 4; ++j) {
      #pragma unroll
      for (int r = 0; r < 8; ++r) {
        float x = (j == 0) ? xv[r].x : (j == 1) ? xv[r].y
                : (j == 2) ? xv[r].z : xv[r].w;
        acc[r][0] = fmaf(x, w[j].x, acc[r][0]);
        acc[r][1] = fmaf(x, w[j].y, acc[r][1]);
        acc[r][2] = fmaf(x, w[j].z, acc[r][2]);
        acc[r][3] = fmaf(x, w[j].w, acc[r][3]);
      }
    }
  }

  // bias + relu -> wave-private LDS rows; float4-group g stored at (g ^ r)
  {
    float4 bb = ((const float4*)(ws + B1_OFF))[lane];
    #pragma unroll
    for (int r = 0; r < 8; ++r) {
      float4 hv;
      hv.x = acc[r][0] + bb.x; hv.y = acc[r][1] + bb.y;
      hv.z = acc[r][2] + bb.z; hv.w = acc[r][3] + bb.w;
      hv.x = hv.x > 0.0f ? hv.x : 0.0f;
      hv.y = hv.y > 0.0f ? hv.y : 0.0f;
      hv.z = hv.z > 0.0f ? hv.z : 0.0f;
      hv.w = hv.w > 0.0f ? hv.w : 0.0f;
      *(float4*)&s_h[wvu * 8 + r][(lane ^ r) << 2] = hv;
    }
  }

  // ---- layer 2: h2 = relu(h1 @ W2^T + b2), K = 256
  #pragma unroll
  for (int r = 0; r < 8; ++r)
    #pragma unroll
    for (int c = 0; c < 4; ++c) acc[r][c] = 0.0f;

  #pragma unroll 2
  for (int k0 = 0; k0 < HID; k0 += 4) {
    float4 w[4];
    #pragma unroll
    for (int j = 0; j < 4; ++j) w[j] = W2T4[(k0 + j) * 64 + lane];
    float4 xv[8];
    #pragma unroll
    for (int r = 0; r < 8; ++r)                       // uniform LDS address ->
      xv[r] = *(const float4*)&s_h[wvu * 8 + r][(((k0 >> 2) ^ r) << 2)];  // broadcast
    #pragma unroll
    for (int j = 0; j < 4; ++j) {
      #pragma unroll
      for (int r = 0; r < 8; ++r) {
        float x = (j == 0) ? xv[r].x : (j == 1) ? xv[r].y
                : (j == 2) ? xv[r].z : xv[r].w;
        acc[r][0] = fmaf(x, w[j].x, acc[r][0]);
        acc[r][1] = fmaf(x, w[j].y, acc[r][1]);
        acc[r][2] = fmaf(x, w[j].z, acc[r][2]);
        acc[r][3] = fmaf(x, w[j].w, acc[r][3]);
      }
    }
  }

  // bias + relu -> h2 into the SAME LDS rows (all h1 reads done, program order)
  {
    float4 bb = ((const float4*)(ws + B2_OFF))[lane];
    #pragma unroll
    for (int r = 0; r < 8; ++r) {
      float4 hv;
      hv.x = acc[r][0] + bb.x; hv.y = acc[r][1] + bb.y;
      hv.z = acc[r][2] + bb.z; hv.w = acc[r][3] + bb.w;
      hv.x = hv.x > 0.0f ? hv.x : 0.0f;
      hv.y = hv.y > 0.0f ? hv.y : 0.0f;
      hv.z = hv.z > 0.0f ? hv.z : 0.0f;
      hv.w = hv.w > 0.0f ? hv.w : 0.0f;
      *(float4*)&s_h[wvu * 8 + r][(lane ^ r) << 2] = hv;
    }
  }

  // ---- layer 3 (K=256, N=16) + epilogue. Lane -> (row = lane>>3, action = lane&7),
  // both u and s chains serial k-ascending (matches sgemm).
  {
    const int r3 = lane >> 3;
    const int a  = lane & 7;
    const float* __restrict__ h2row = &s_h[wvu * 8 + r3][0];
    float accu = 0.0f, accs = 0.0f;
    #pragma unroll 2
    for (int k0 = 0; k0 < HID; k0 += 4) {
      const int col = ((k0 >> 2) ^ r3) << 2;          // XOR layout; 8 rows -> 8 banks
      v2f ha = *(const v2f*)(h2row + col);            // k0, k0+1 (8-lane broadcast)
      v2f hb = *(const v2f*)(h2row + col + 2);        // k0+2, k0+3
      v2f wp0 = W3P[(k0 + 0) * 8 + a];
      v2f wp1 = W3P[(k0 + 1) * 8 + a];
      v2f wp2 = W3P[(k0 + 2) * 8 + a];
      v2f wp3 = W3P[(k0 + 3) * 8 + a];
      accu = fmaf(ha.x, wp0.x, accu); accs = fmaf(ha.x, wp0.y, accs);
      accu = fmaf(ha.y, wp1.x, accu); accs = fmaf(ha.y, wp1.y, accs);
      accu = fmaf(hb.x, wp2.x, accu); accs = fmaf(hb.x, wp2.y, accs);
      accu = fmaf(hb.y, wp3.x, accu); accs = fmaf(hb.y, wp3.y, accs);
    }
    v2f b3p = ((const v2f*)(ws + B3P_OFF))[a];
    float nu = accu + b3p.x;
    float ns = accs + b3p.y;

    long grow = wrow + r3;
    float sa = fabsf(ns);
    float ev = eps[grow * AD + a];                // coalesced: base + lane
    float t  = __fmul_rn(sa, ev);                 // separately-rounded mul
    float z  = __fadd_rn(nu, t);                  // separately-rounded add
    float e  = (float)exp(-(double)z);            // correctly-rounded expf near boundary
    float d  = __fadd_rn(1.0f, e);
    float act = 1.0f / d;
    float q  = act * 8.0f;                        // exact
    float wq = __fadd_rn(q, 1.0f);
    out[grow * AD + a] = (int)wq;                 // truncation, as astype(int32)
  }
}

extern "C" void kernel_launch(void* const* d_in, const int* in_sizes, int n_in,
                              void* d_out, int out_size, void* d_ws, size_t ws_size,
                              hipStream_t stream) {
  const float* state = (const float*)d_in[0];
  const float* W1    = (const float*)d_in[1];
  const float* b1    = (const float*)d_in[2];
  const float* W2    = (const float*)d_in[3];
  const float* b2    = (const float*)d_in[4];
  const float* W3    = (const float*)d_in[5];
  const float* b3    = (const float*)d_in[6];
  const float* eps   = (const float*)d_in[7];
  int*   out = (int*)d_out;
  float* ws  = (float*)d_ws;   // 411,712 bytes; rebuilt every launch

  hipLaunchKernelGGL(prep_weights, dim3(128), dim3(256), 0, stream,
                     W1, b1, W2, b2, W3, b3, ws);
  hipLaunchKernelGGL(actor_fused, dim3(NB / 16), dim3(128), 0, stream,
                     state, eps, ws, out);
}

// Round 4
// 880.127 us; speedup vs baseline: 1.0219x; 1.0219x over previous
//
#include <hip/hip_runtime.h>
#include <math.h>

// Problem constants
#define NB  262144   // batch
#define SD  128      // STATE_DIM
#define HID 256      // HIDDEN
#define AD  8        // ACTION_DIM

typedef float v2f __attribute__((ext_vector_type(2)));

// d_ws layout (floats)
#define W1T_OFF 0                       // [SD][HID]   W1T[k*HID+j] = W1[j*SD+k]
#define W2T_OFF (SD*HID)                // [HID][HID]  32768
#define W3P_OFF (W2T_OFF + HID*HID)     // [HID][AD] float2 pairs (u,s): 98304, 4096 floats
#define B1_OFF  (W3P_OFF + HID*2*AD)    // 102400
#define B2_OFF  (B1_OFF + HID)          // 102656
#define B3P_OFF (B2_OFF + HID)          // 102912, [AD] float2 pairs
#define WS_FLOATS (B3P_OFF + 2*AD)      // 102928 floats = 411,712 bytes

__global__ __launch_bounds__(256) void prep_weights(
    const float* __restrict__ W1, const float* __restrict__ b1,
    const float* __restrict__ W2, const float* __restrict__ b2,
    const float* __restrict__ W3, const float* __restrict__ b3,
    float* __restrict__ ws) {
  int stride = gridDim.x * blockDim.x;
  for (int i = blockIdx.x * blockDim.x + threadIdx.x; i < WS_FLOATS; i += stride) {
    float v;
    if (i < W2T_OFF) {                       // W1T
      int k = i >> 8, j = i & 255;
      v = W1[j * SD + k];
    } else if (i < W3P_OFF) {                // W2T
      int t = i - W2T_OFF;
      int k = t >> 8, j = t & 255;
      v = W2[j * HID + k];
    } else if (i < B1_OFF) {                 // W3P[k][a] = (W3[a][k], W3[a+8][k])
      int t = i - W3P_OFF;
      int k = t >> 4, a = (t >> 1) & 7, h = t & 1;
      v = W3[(a + 8 * h) * HID + k];
    } else if (i < B2_OFF) {
      v = b1[i - B1_OFF];
    } else if (i < B3P_OFF) {
      v = b2[i - B2_OFF];
    } else {                                 // B3P[a] = (b3[a], b3[a+8])
      int t = i - B3P_OFF;
      v = b3[(t >> 1) + 8 * (t & 1)];
    }
    ws[i] = v;
  }
}

// R8 post-mortem chain:
//  R6 (256,5)+pk_fma: VGPR 48, WRITE +40MB -> blamed the asm. WRONG.
//  R7 (128,5)+fmaf:   VGPR 48, WRITE +81MB -> the spiller is min_waves=5:
//    allocator budgets 256 arch-VGPRs/SIMD, 256/5 -> 48-reg cap < ~52 live.
//    Spill scratch also capped residency (Occ 46.9% vs 62.5% theoretical).
//  R8: keep the good parts of R7 (128-thread/2-wave blocks, [16][256]
//    XOR-swizzled LDS = 16 KiB -> 10 blocks/CU = 20 waves/CU), but
//    __launch_bounds__(128,4): cap 256/4 = 64 >= 52 -> NO spill, and actual
//    usage ~52 (<=64) lets HW hold 8 waves/SIMD, so LDS is the binding cap.
//
// Structure: 8 rows/wave, 16 rows/block. LDS reused h1 -> h2; wave-private
// rows -> NO barriers. Layer-2 reads are wave-uniform LDS broadcasts; the
// XOR float4-group layout (g ^ r) makes layer-3's 8 row-slices hit 8 banks.
__global__ __launch_bounds__(128, 4) void actor_fused(
    const float* __restrict__ state, const float* __restrict__ eps,
    const float* __restrict__ ws, int* __restrict__ out) {
  __shared__ float s_h[16][256];   // 16,384 B

  const int tid  = threadIdx.x;
  const int lane = tid & 63;
  const int wvu  = __builtin_amdgcn_readfirstlane(tid >> 6);  // 0..1, uniform
  const long wrow = (long)blockIdx.x * 16 + wvu * 8;          // wave's first row

  const float4* __restrict__ W1T4 = (const float4*)(ws + W1T_OFF);  // [SD][64]
  const float4* __restrict__ W2T4 = (const float4*)(ws + W2T_OFF);  // [HID][64]
  const v2f*    __restrict__ W3P  = (const v2f*)(ws + W3P_OFF);     // [HID][8]

  const float* __restrict__ xbase = state + wrow * SD;   // uniform pointer

  // ---- layer 1: h1 = relu(x @ W1^T + b1), K = 128
  float acc[8][4];
  #pragma unroll
  for (int r = 0; r < 8; ++r)
    #pragma unroll
    for (int c = 0; c < 4; ++c) acc[r][c] = 0.0f;

  #pragma unroll 2
  for (int k0 = 0; k0 < SD; k0 += 4) {
    float4 w[4];
    #pragma unroll
    for (int j = 0; j < 4; ++j) w[j] = W1T4[(k0 + j) * 64 + lane];
    float4 xv[8];
    #pragma unroll
    for (int r = 0; r < 8; ++r)                       // uniform address: one line
      xv[r] = *(const float4*)(xbase + r * SD + k0);  // serves the whole wave
    #pragma unroll
    for (int j = 0; j < 4; ++j) {
      #pragma unroll
      for (int r = 0; r < 8; ++r) {
        float x = (j == 0) ? xv[r].x : (j == 1) ? xv[r].y
                : (j == 2) ? xv[r].z : xv[r].w;
        acc[r][0] = fmaf(x, w[j].x, acc[r][0]);
        acc[r][1] = fmaf(x, w[j].y, acc[r][1]);
        acc[r][2] = fmaf(x, w[j].z, acc[r][2]);
        acc[r][3] = fmaf(x, w[j].w, acc[r][3]);
      }
    }
  }

  // bias + relu -> wave-private LDS rows; float4-group g stored at (g ^ r)
  {
    float4 bb = ((const float4*)(ws + B1_OFF))[lane];
    #pragma unroll
    for (int r = 0; r < 8; ++r) {
      float4 hv;
      hv.x = acc[r][0] + bb.x; hv.y = acc[r][1] + bb.y;
      hv.z = acc[r][2] + bb.z; hv.w = acc[r][3] + bb.w;
      hv.x = hv.x > 0.0f ? hv.x : 0.0f;
      hv.y = hv.y > 0.0f ? hv.y : 0.0f;
      hv.z = hv.z > 0.0f ? hv.z : 0.0f;
      hv.w = hv.w > 0.0f ? hv.w : 0.0f;
      *(float4*)&s_h[wvu * 8 + r][(lane ^ r) << 2] = hv;
    }
  }

  // ---- layer 2: h2 = relu(h1 @ W2^T + b2), K = 256
  #pragma unroll
  for (int r = 0; r < 8; ++r)
    #pragma unroll
    for (int c = 0; c < 4; ++c) acc[r][c] = 0.0f;

  #pragma unroll 2
  for (int k0 = 0; k0 < HID; k0 += 4) {
    float4 w[4];
    #pragma unroll
    for (int j = 0; j < 4; ++j) w[j] = W2T4[(k0 + j) * 64 + lane];
    float4 xv[8];
    #pragma unroll
    for (int r = 0; r < 8; ++r)                       // uniform LDS address ->
      xv[r] = *(const float4*)&s_h[wvu * 8 + r][(((k0 >> 2) ^ r) << 2)];  // broadcast
    #pragma unroll
    for (int j = 0; j < 4; ++j) {
      #pragma unroll
      for (int r = 0; r < 8; ++r) {
        float x = (j == 0) ? xv[r].x : (j == 1) ? xv[r].y
                : (j == 2) ? xv[r].z : xv[r].w;
        acc[r][0] = fmaf(x, w[j].x, acc[r][0]);
        acc[r][1] = fmaf(x, w[j].y, acc[r][1]);
        acc[r][2] = fmaf(x, w[j].z, acc[r][2]);
        acc[r][3] = fmaf(x, w[j].w, acc[r][3]);
      }
    }
  }

  // bias + relu -> h2 into the SAME LDS rows (all h1 reads done, program order)
  {
    float4 bb = ((const float4*)(ws + B2_OFF))[lane];
    #pragma unroll
    for (int r = 0; r < 8; ++r) {
      float4 hv;
      hv.x = acc[r][0] + bb.x; hv.y = acc[r][1] + bb.y;
      hv.z = acc[r][2] + bb.z; hv.w = acc[r][3] + bb.w;
      hv.x = hv.x > 0.0f ? hv.x : 0.0f;
      hv.y = hv.y > 0.0f ? hv.y : 0.0f;
      hv.z = hv.z > 0.0f ? hv.z : 0.0f;
      hv.w = hv.w > 0.0f ? hv.w : 0.0f;
      *(float4*)&s_h[wvu * 8 + r][(lane ^ r) << 2] = hv;
    }
  }

  // ---- layer 3 (K=256, N=16) + epilogue. Lane -> (row = lane>>3, action = lane&7),
  // both u and s chains serial k-ascending (matches sgemm).
  {
    const int r3 = lane >> 3;
    const int a  = lane & 7;
    const float* __restrict__ h2row = &s_h[wvu * 8 + r3][0];
    float accu = 0.0f, accs = 0.0f;
    #pragma unroll 2
    for (int k0 = 0; k0 < HID; k0 += 4) {
      const int col = ((k0 >> 2) ^ r3) << 2;          // XOR layout; 8 rows -> 8 banks
      v2f ha = *(const v2f*)(h2row + col);            // k0, k0+1 (8-lane broadcast)
      v2f hb = *(const v2f*)(h2row + col + 2);        // k0+2, k0+3
      v2f wp0 = W3P[(k0 + 0) * 8 + a];
      v2f wp1 = W3P[(k0 + 1) * 8 + a];
      v2f wp2 = W3P[(k0 + 2) * 8 + a];
      v2f wp3 = W3P[(k0 + 3) * 8 + a];
      accu = fmaf(ha.x, wp0.x, accu); accs = fmaf(ha.x, wp0.y, accs);
      accu = fmaf(ha.y, wp1.x, accu); accs = fmaf(ha.y, wp1.y, accs);
      accu = fmaf(hb.x, wp2.x, accu); accs = fmaf(hb.x, wp2.y, accs);
      accu = fmaf(hb.y, wp3.x, accu); accs = fmaf(hb.y, wp3.y, accs);
    }
    v2f b3p = ((const v2f*)(ws + B3P_OFF))[a];
    float nu = accu + b3p.x;
    float ns = accs + b3p.y;

    long grow = wrow + r3;
    float sa = fabsf(ns);
    float ev = eps[grow * AD + a];                // coalesced: base + lane
    float t  = __fmul_rn(sa, ev);                 // separately-rounded mul
    float z  = __fadd_rn(nu, t);                  // separately-rounded add
    float e  = (float)exp(-(double)z);            // correctly-rounded expf near boundary
    float d  = __fadd_rn(1.0f, e);
    float act = 1.0f / d;
    float q  = act * 8.0f;                        // exact
    float wq = __fadd_rn(q, 1.0f);
    out[grow * AD + a] = (int)wq;                 // truncation, as astype(int32)
  }
}

extern "C" void kernel_launch(void* const* d_in, const int* in_sizes, int n_in,
                              void* d_out, int out_size, void* d_ws, size_t ws_size,
                              hipStream_t stream) {
  const float* state = (const float*)d_in[0];
  const float* W1    = (const float*)d_in[1];
  const float* b1    = (const float*)d_in[2];
  const float* W2    = (const float*)d_in[3];
  const float* b2    = (const float*)d_in[4];
  const float* W3    = (const float*)d_in[5];
  const float* b3    = (const float*)d_in[6];
  const float* eps   = (const float*)d_in[7];
  int*   out = (int*)d_out;
  float* ws  = (float*)d_ws;   // 411,712 bytes; rebuilt every launch

  hipLaunchKernelGGL(prep_weights, dim3(128), dim3(256), 0, stream,
                     W1, b1, W2, b2, W3, b3, ws);
  hipLaunchKernelGGL(actor_fused, dim3(NB / 16), dim3(128), 0, stream,
                     state, eps, ws, out);
}